// Round 1
// baseline (13040.454 us; speedup 1.0000x reference)
//
#include <hip/hip_runtime.h>
#include <hip/hip_bf16.h>
#include <stdint.h>

#define BB 32
#define PP 196
#define ENC 512
#define DEC 512
#define ATTD 512
#define EE 256
#define SS 128
#define VV 10000
#define TT 127   // S-1 steps

typedef unsigned short ushort_t;
typedef unsigned int uint_t;
typedef float f32x4 __attribute__((ext_vector_type(4)));
typedef short s16x8 __attribute__((ext_vector_type(8)));

__device__ __forceinline__ float bf2f(ushort_t u) {
    uint_t x = ((uint_t)u) << 16;
    return __uint_as_float(x);
}
__device__ __forceinline__ ushort_t f2bf(float f) {
    uint_t u = __float_as_uint(f);
    uint_t r = (u + 0x7FFFu + ((u >> 16) & 1u)) >> 16;
    return (ushort_t)r;
}
__device__ __forceinline__ float ftanh(float x) {
    x = fminf(15.f, fmaxf(-15.f, x));
    float e = __expf(2.f * x);
    return (e - 1.f) / (e + 1.f);
}
__device__ __forceinline__ float fsig(float x) {
    return 1.f / (1.f + __expf(-x));
}

// ---------------- prep kernels ----------------

__global__ void k_cvt(const float* __restrict__ s, ushort_t* __restrict__ d, int n) {
    for (int i = blockIdx.x * blockDim.x + threadIdx.x; i < n; i += gridDim.x * blockDim.x)
        d[i] = f2bf(s[i]);
}

// embeds[t][b][e] = emb[cap[b*S + t]][e], t < 127
__global__ void k_embed(const int* __restrict__ cap, const float* __restrict__ emb,
                        float* __restrict__ embeds) {
    const int n = TT * BB * EE;
    for (int i = blockIdx.x * blockDim.x + threadIdx.x; i < n; i += gridDim.x * blockDim.x) {
        int e = i & (EE - 1);
        int b = (i >> 8) & (BB - 1);
        int t = i >> 13;
        int tok = cap[b * SS + t];
        embeds[i] = emb[(size_t)tok * EE + e];
    }
}

// per-b: mean over P, then h0/c0 = mean @ W_init_{h,c} + b
__global__ __launch_bounds__(256) void k_init(const float* __restrict__ feat,
                                              const float* __restrict__ Wh, const float* __restrict__ bh,
                                              const float* __restrict__ Wc, const float* __restrict__ bc,
                                              float* __restrict__ h0, float* __restrict__ c0) {
    __shared__ float ms[ENC];
    int b = blockIdx.x, t = threadIdx.x;
    for (int c = t; c < ENC; c += 256) {
        float s = 0.f;
        for (int p = 0; p < PP; ++p) s += feat[((size_t)b * PP + p) * ENC + c];
        ms[c] = s * (1.f / (float)PP);
    }
    __syncthreads();
    int d0 = 2 * t;
    float ah0 = 0.f, ah1 = 0.f, ac0 = 0.f, ac1 = 0.f;
    for (int k = 0; k < ENC; ++k) {
        float mk = ms[k];
        float2 wh = *(const float2*)(Wh + (size_t)k * DEC + d0);
        float2 wc = *(const float2*)(Wc + (size_t)k * DEC + d0);
        ah0 += mk * wh.x; ah1 += mk * wh.y;
        ac0 += mk * wc.x; ac1 += mk * wc.y;
    }
    h0[b * DEC + d0] = ah0 + bh[d0];
    h0[b * DEC + d0 + 1] = ah1 + bh[d0 + 1];
    c0[b * DEC + d0] = ac0 + bc[d0];
    c0[b * DEC + d0 + 1] = ac1 + bc[d0 + 1];
}

// ---------------- bf16 MFMA GEMM (128x128 tile, BK=32, 4 waves) ----------------
// MODE 0: out = bf16 [M][N], bias added (feat_proj)
// MODE 1: out = f32 scattered: row r = t*32+b -> outf[(b*127+t)*V + col], bias added
template <int MODE>
__global__ __launch_bounds__(256) void k_gemm(const ushort_t* __restrict__ A,
                                              const ushort_t* __restrict__ Bm,
                                              const float* __restrict__ bias,
                                              ushort_t* __restrict__ outb,
                                              float* __restrict__ outf,
                                              int M, int N, int K) {
    __shared__ __align__(16) ushort_t As[128 * 32];   // [row][k]
    __shared__ __align__(16) ushort_t Bs[128 * 32];   // [col][k] (transposed)

    const int tid = threadIdx.x;
    const int wid = tid >> 6, lane = tid & 63;
    const int wm = wid >> 1, wn = wid & 1;
    const int lr = lane & 15, lk = (lane >> 4) * 8;
    const int row0 = blockIdx.x * 128, col0 = blockIdx.y * 128;

    f32x4 acc[4][4];
#pragma unroll
    for (int i = 0; i < 4; ++i)
#pragma unroll
        for (int j = 0; j < 4; ++j) acc[i][j] = (f32x4){0.f, 0.f, 0.f, 0.f};

    for (int k0 = 0; k0 < K; k0 += 32) {
        // stage A: thread -> row = tid/2, kchunk = (tid&1)*16
        {
            int r = tid >> 1, kk = (tid & 1) * 16;
            int gr = row0 + r;
            uint4 v0 = {0, 0, 0, 0}, v1 = {0, 0, 0, 0};
            if (gr < M) {
                const ushort_t* sp = A + (size_t)gr * K + k0 + kk;
                v0 = *(const uint4*)sp;
                v1 = *(const uint4*)(sp + 8);
            }
            *(uint4*)(As + r * 32 + kk) = v0;
            *(uint4*)(As + r * 32 + kk + 8) = v1;
        }
        // stage B (transposed): thread -> k = tid/8, ncols = (tid&7)*16 .. +16
        {
            int kk = tid >> 3;
            int n = (tid & 7) * 16;
            const ushort_t* sp = Bm + (size_t)(k0 + kk) * N + col0 + n;
            ushort_t tmp[16];
            if (col0 + n + 16 <= N) {
                *(uint4*)tmp = *(const uint4*)sp;
                *(uint4*)(tmp + 8) = *(const uint4*)(sp + 8);
            } else {
#pragma unroll
                for (int j = 0; j < 16; ++j) {
                    int c = col0 + n + j;
                    tmp[j] = (c < N) ? sp[j] : (ushort_t)0;
                }
            }
#pragma unroll
            for (int j = 0; j < 16; ++j) Bs[(n + j) * 32 + kk] = tmp[j];
        }
        __syncthreads();
        s16x8 af[4], bfr[4];
#pragma unroll
        for (int i = 0; i < 4; ++i)
            af[i] = *(const s16x8*)(As + (wm * 64 + i * 16 + lr) * 32 + lk);
#pragma unroll
        for (int j = 0; j < 4; ++j)
            bfr[j] = *(const s16x8*)(Bs + (wn * 64 + j * 16 + lr) * 32 + lk);
#pragma unroll
        for (int i = 0; i < 4; ++i)
#pragma unroll
            for (int j = 0; j < 4; ++j)
                acc[i][j] = __builtin_amdgcn_mfma_f32_16x16x32_bf16(af[i], bfr[j], acc[i][j], 0, 0, 0);
        __syncthreads();
    }

    const int lrow = (lane >> 4) * 4;
#pragma unroll
    for (int i = 0; i < 4; ++i) {
#pragma unroll
        for (int j = 0; j < 4; ++j) {
            int gr0 = row0 + wm * 64 + i * 16 + lrow;
            int gc = col0 + wn * 64 + j * 16 + lr;
#pragma unroll
            for (int r = 0; r < 4; ++r) {
                int gr = gr0 + r;
                if (gr < M && gc < N) {
                    float v = acc[i][j][r] + bias[gc];
                    if (MODE == 0) {
                        outb[(size_t)gr * N + gc] = f2bf(v);
                    } else {
                        int t = gr >> 5, b = gr & 31;
                        outf[((size_t)(b * TT + t)) * VV + gc] = v;
                    }
                }
            }
        }
    }
}

// ---------------- per-step kernels ----------------

// one block per b: a = h@W_dec + b_dec; scores = tanh(fp+a).v + b_full; softmax; context
__global__ __launch_bounds__(256) void k_att(const ushort_t* __restrict__ fp,
                                             const ushort_t* __restrict__ fb,
                                             const ushort_t* __restrict__ Wdec,
                                             const float* __restrict__ bdec,
                                             const float* __restrict__ vatt,
                                             const float* __restrict__ bfull,
                                             const float* __restrict__ h_in,
                                             float* __restrict__ ctx) {
    __shared__ float hs[DEC];
    __shared__ float vs[ATTD];
    __shared__ float as_[ATTD];
    __shared__ float sc[256];
    __shared__ float red[256];
    const int b = blockIdx.x, t = threadIdx.x;

    hs[t] = h_in[b * DEC + t];
    hs[t + 256] = h_in[b * DEC + t + 256];
    vs[t] = vatt[t];
    vs[t + 256] = vatt[t + 256];
    __syncthreads();

    // a = h @ W_dec_att + b_dec  (thread handles cols 2t, 2t+1)
    {
        const int n0 = 2 * t;
        float a0 = 0.f, a1 = 0.f;
#pragma unroll 8
        for (int k = 0; k < DEC; ++k) {
            uint_t w = *(const uint_t*)(Wdec + (size_t)k * ATTD + n0);
            float hk = hs[k];
            a0 += hk * bf2f((ushort_t)(w & 0xffffu));
            a1 += hk * bf2f((ushort_t)(w >> 16));
        }
        as_[n0] = a0 + bdec[n0];
        as_[n0 + 1] = a1 + bdec[n0 + 1];
    }
    __syncthreads();

    // scores (one p per thread, p < 196)
    float sval = -3.0e38f;
    if (t < PP) {
        const ushort_t* fr = fp + ((size_t)b * PP + t) * ATTD;
        float acc = 0.f;
#pragma unroll 8
        for (int kk = 0; kk < ATTD; kk += 2) {
            uint_t fv = *(const uint_t*)(fr + kk);
            float f0 = bf2f((ushort_t)(fv & 0xffffu));
            float f1 = bf2f((ushort_t)(fv >> 16));
            acc += ftanh(f0 + as_[kk]) * vs[kk];
            acc += ftanh(f1 + as_[kk + 1]) * vs[kk + 1];
        }
        sval = acc + bfull[0];
    }
    sc[t] = sval;
    red[t] = sval;
    __syncthreads();
    for (int s = 128; s > 0; s >>= 1) {
        if (t < s) red[t] = fmaxf(red[t], red[t + s]);
        __syncthreads();
    }
    const float m = red[0];
    __syncthreads();
    float e = (t < PP) ? __expf(sc[t] - m) : 0.f;
    red[t] = e;
    __syncthreads();
    for (int s = 128; s > 0; s >>= 1) {
        if (t < s) red[t] += red[t + s];
        __syncthreads();
    }
    const float inv = 1.f / red[0];
    sc[t] = e * inv;   // alpha
    __syncthreads();

    // context = alpha @ features (cols 2t, 2t+1)
    {
        const int e0 = 2 * t;
        float x0 = 0.f, x1 = 0.f;
#pragma unroll 4
        for (int p = 0; p < PP; ++p) {
            float al = sc[p];
            uint_t fv = *(const uint_t*)(fb + ((size_t)b * PP + p) * ENC + e0);
            x0 += al * bf2f((ushort_t)(fv & 0xffffu));
            x1 += al * bf2f((ushort_t)(fv >> 16));
        }
        ctx[b * ENC + e0] = x0;
        ctx[b * ENC + e0 + 1] = x1;
    }
}

// 256 blocks (dz: 2 d's each) x 256 threads; thread = (b, gate, ds), full-K dot; fused pointwise
__global__ __launch_bounds__(256) void k_gates(const float* __restrict__ xe_t,
                                               const float* __restrict__ ctx,
                                               const float* __restrict__ h_in,
                                               const float* __restrict__ Wih,
                                               const float* __restrict__ Whh,
                                               const float* __restrict__ bih,
                                               const float* __restrict__ bhh,
                                               float* __restrict__ cbuf,
                                               float* __restrict__ h_out,
                                               ushort_t* __restrict__ Hb_t) {
    __shared__ float gs[256];
    const int dz = blockIdx.x, tid = threadIdx.x;
    const int b = tid >> 3, g = (tid >> 1) & 3, ds = tid & 1;
    const int d = dz * 2 + ds;
    const int row = g * DEC + d;
    const float* wi = Wih + (size_t)row * (EE + ENC);
    const float* wh = Whh + (size_t)row * DEC;
    const float* xe = xe_t + b * EE;
    const float* xc = ctx + b * ENC;
    const float* xh = h_in + b * DEC;

    float acc = bih[row] + bhh[row];
#pragma unroll 4
    for (int k = 0; k < EE; k += 4) {
        float4 w = *(const float4*)(wi + k);
        float4 x = *(const float4*)(xe + k);
        acc += w.x * x.x + w.y * x.y + w.z * x.z + w.w * x.w;
    }
#pragma unroll 4
    for (int k = 0; k < ENC; k += 4) {
        float4 w = *(const float4*)(wi + EE + k);
        float4 x = *(const float4*)(xc + k);
        acc += w.x * x.x + w.y * x.y + w.z * x.z + w.w * x.w;
    }
#pragma unroll 4
    for (int k = 0; k < DEC; k += 4) {
        float4 w = *(const float4*)(wh + k);
        float4 x = *(const float4*)(xh + k);
        acc += w.x * x.x + w.y * x.y + w.z * x.z + w.w * x.w;
    }
    gs[tid] = acc;
    __syncthreads();
    if (tid < 64) {
        const int b2 = tid >> 1, d2s = tid & 1;
        const int dd = dz * 2 + d2s;
        const int base = b2 * 8 + d2s;
        float vi = gs[base + 0], vf = gs[base + 2], vg = gs[base + 4], vo = gs[base + 6];
        float cold = cbuf[b2 * DEC + dd];
        float cn = fsig(vf) * cold + fsig(vi) * ftanh(vg);
        float hn = fsig(vo) * ftanh(cn);
        cbuf[b2 * DEC + dd] = cn;
        h_out[b2 * DEC + dd] = hn;
        Hb_t[b2 * DEC + dd] = f2bf(hn);
    }
}

// ---------------- launch ----------------

extern "C" void kernel_launch(void* const* d_in, const int* in_sizes, int n_in,
                              void* d_out, int out_size, void* d_ws, size_t ws_size,
                              hipStream_t stream) {
    const float* features  = (const float*)d_in[0];
    const int*   captions  = (const int*)d_in[1];
    const float* emb       = (const float*)d_in[2];
    const float* W_enc_att = (const float*)d_in[3];
    const float* b_enc_att = (const float*)d_in[4];
    const float* W_dec_att = (const float*)d_in[5];
    const float* b_dec_att = (const float*)d_in[6];
    const float* v_att     = (const float*)d_in[7];
    const float* b_full    = (const float*)d_in[8];
    const float* W_init_h  = (const float*)d_in[9];
    const float* b_init_h  = (const float*)d_in[10];
    const float* W_init_c  = (const float*)d_in[11];
    const float* b_init_c  = (const float*)d_in[12];
    const float* W_ih      = (const float*)d_in[13];
    const float* W_hh      = (const float*)d_in[14];
    const float* b_ih      = (const float*)d_in[15];
    const float* b_hh      = (const float*)d_in[16];
    const float* W_fcn     = (const float*)d_in[17];
    const float* b_fcn     = (const float*)d_in[18];
    float* out = (float*)d_out;
    char* ws = (char*)d_ws;

    size_t o = 0;
    ushort_t* Wfcn_b = (ushort_t*)(ws + o); o += (size_t)DEC * VV * 2;        // 10,240,000
    ushort_t* Wenc_b = (ushort_t*)(ws + o); o += (size_t)ENC * ATTD * 2;      // 524,288
    ushort_t* Wdec_b = (ushort_t*)(ws + o); o += (size_t)DEC * ATTD * 2;      // 524,288
    ushort_t* fb     = (ushort_t*)(ws + o); o += (size_t)BB * PP * ENC * 2;   // 6,422,528
    ushort_t* fp_b   = (ushort_t*)(ws + o); o += (size_t)BB * PP * ATTD * 2;  // 6,422,528
    float*    embeds = (float*)(ws + o);    o += (size_t)TT * BB * EE * 4;    // 4,161,536
    ushort_t* Hb     = (ushort_t*)(ws + o); o += (size_t)TT * BB * DEC * 2;   // 4,161,536
    float*    hbuf   = (float*)(ws + o);    o += (size_t)2 * BB * DEC * 4;    // 131,072
    float*    cbuf   = (float*)(ws + o);    o += (size_t)BB * DEC * 4;        // 65,536
    float*    ctx    = (float*)(ws + o);    o += (size_t)BB * ENC * 4;        // 65,536

    // prep
    k_cvt<<<2048, 256, 0, stream>>>(W_fcn, Wfcn_b, DEC * VV);
    k_cvt<<<256, 256, 0, stream>>>(W_enc_att, Wenc_b, ENC * ATTD);
    k_cvt<<<256, 256, 0, stream>>>(W_dec_att, Wdec_b, DEC * ATTD);
    k_cvt<<<2048, 256, 0, stream>>>(features, fb, BB * PP * ENC);
    k_embed<<<1024, 256, 0, stream>>>(captions, emb, embeds);
    k_init<<<32, 256, 0, stream>>>(features, W_init_h, b_init_h, W_init_c, b_init_c,
                                   hbuf, cbuf);
    // feat_proj = features @ W_enc_att + b_enc_att  (bf16 out)
    k_gemm<0><<<dim3((BB * PP) / 128, ATTD / 128), 256, 0, stream>>>(
        fb, Wenc_b, b_enc_att, fp_b, nullptr, BB * PP, ATTD, ENC);

    // recurrent steps
    for (int t = 0; t < TT; ++t) {
        const float* h_in = hbuf + (size_t)(t & 1) * BB * DEC;
        float* h_out = hbuf + (size_t)((t + 1) & 1) * BB * DEC;
        k_att<<<32, 256, 0, stream>>>(fp_b, fb, Wdec_b, b_dec_att, v_att, b_full,
                                      h_in, ctx);
        k_gates<<<256, 256, 0, stream>>>(embeds + (size_t)t * BB * EE, ctx, h_in,
                                         W_ih, W_hh, b_ih, b_hh,
                                         cbuf, h_out, Hb + (size_t)t * BB * DEC);
    }

    // out = H @ W_fcn + b_fcn, scattered to [b][t][v]
    k_gemm<1><<<dim3((TT * BB + 127) / 128, (VV + 127) / 128), 256, 0, stream>>>(
        Hb, Wfcn_b, b_fcn, nullptr, out, TT * BB, VV, DEC);
}

// Round 2
// 8553.542 us; speedup vs baseline: 1.5246x; 1.5246x over previous
//
#include <hip/hip_runtime.h>
#include <hip/hip_bf16.h>
#include <stdint.h>

#define BB 32
#define PP 196
#define ENC 512
#define DEC 512
#define ATTD 512
#define EE 256
#define SS 128
#define VV 10000
#define TT 127   // S-1 steps

typedef unsigned short ushort_t;
typedef unsigned int uint_t;
typedef float f32x4 __attribute__((ext_vector_type(4)));
typedef short s16x8 __attribute__((ext_vector_type(8)));

__device__ __forceinline__ float bf2f(ushort_t u) {
    uint_t x = ((uint_t)u) << 16;
    return __uint_as_float(x);
}
__device__ __forceinline__ ushort_t f2bf(float f) {
    uint_t u = __float_as_uint(f);
    uint_t r = (u + 0x7FFFu + ((u >> 16) & 1u)) >> 16;
    return (ushort_t)r;
}
__device__ __forceinline__ float ftanh(float x) {
    x = fminf(15.f, fmaxf(-15.f, x));
    float e = __expf(2.f * x);
    return (e - 1.f) / (e + 1.f);
}
__device__ __forceinline__ float fsig(float x) {
    return 1.f / (1.f + __expf(-x));
}

// ---------------- prep kernels ----------------

__global__ void k_cvt(const float* __restrict__ s, ushort_t* __restrict__ d, int n) {
    for (int i = blockIdx.x * blockDim.x + threadIdx.x; i < n; i += gridDim.x * blockDim.x)
        d[i] = f2bf(s[i]);
}

// embeds[t][b][e] = emb[cap[b*S + t]][e], t < 127
__global__ void k_embed(const int* __restrict__ cap, const float* __restrict__ emb,
                        float* __restrict__ embeds) {
    const int n = TT * BB * EE;
    for (int i = blockIdx.x * blockDim.x + threadIdx.x; i < n; i += gridDim.x * blockDim.x) {
        int e = i & (EE - 1);
        int b = (i >> 8) & (BB - 1);
        int t = i >> 13;
        int tok = cap[b * SS + t];
        embeds[i] = emb[(size_t)tok * EE + e];
    }
}

// per-b: mean over P, then h0/c0 = mean @ W_init_{h,c} + b
__global__ __launch_bounds__(256) void k_init(const float* __restrict__ feat,
                                              const float* __restrict__ Wh, const float* __restrict__ bh,
                                              const float* __restrict__ Wc, const float* __restrict__ bc,
                                              float* __restrict__ h0, float* __restrict__ c0) {
    __shared__ float ms[ENC];
    int b = blockIdx.x, t = threadIdx.x;
    for (int c = t; c < ENC; c += 256) {
        float s = 0.f;
        for (int p = 0; p < PP; ++p) s += feat[((size_t)b * PP + p) * ENC + c];
        ms[c] = s * (1.f / (float)PP);
    }
    __syncthreads();
    int d0 = 2 * t;
    float ah0 = 0.f, ah1 = 0.f, ac0 = 0.f, ac1 = 0.f;
    for (int k = 0; k < ENC; ++k) {
        float mk = ms[k];
        float2 wh = *(const float2*)(Wh + (size_t)k * DEC + d0);
        float2 wc = *(const float2*)(Wc + (size_t)k * DEC + d0);
        ah0 += mk * wh.x; ah1 += mk * wh.y;
        ac0 += mk * wc.x; ac1 += mk * wc.y;
    }
    h0[b * DEC + d0] = ah0 + bh[d0];
    h0[b * DEC + d0 + 1] = ah1 + bh[d0 + 1];
    c0[b * DEC + d0] = ac0 + bc[d0];
    c0[b * DEC + d0 + 1] = ac1 + bc[d0 + 1];
}

// ---------------- bf16 MFMA GEMM (128x128 tile, BK=32, 4 waves) ----------------
template <int MODE>
__global__ __launch_bounds__(256) void k_gemm(const ushort_t* __restrict__ A,
                                              const ushort_t* __restrict__ Bm,
                                              const float* __restrict__ bias,
                                              ushort_t* __restrict__ outb,
                                              float* __restrict__ outf,
                                              int M, int N, int K) {
    __shared__ __align__(16) ushort_t As[128 * 32];   // [row][k]
    __shared__ __align__(16) ushort_t Bs[128 * 32];   // [col][k] (transposed)

    const int tid = threadIdx.x;
    const int wid = tid >> 6, lane = tid & 63;
    const int wm = wid >> 1, wn = wid & 1;
    const int lr = lane & 15, lk = (lane >> 4) * 8;
    const int row0 = blockIdx.x * 128, col0 = blockIdx.y * 128;

    f32x4 acc[4][4];
#pragma unroll
    for (int i = 0; i < 4; ++i)
#pragma unroll
        for (int j = 0; j < 4; ++j) acc[i][j] = (f32x4){0.f, 0.f, 0.f, 0.f};

    for (int k0 = 0; k0 < K; k0 += 32) {
        {
            int r = tid >> 1, kk = (tid & 1) * 16;
            int gr = row0 + r;
            uint4 v0 = {0, 0, 0, 0}, v1 = {0, 0, 0, 0};
            if (gr < M) {
                const ushort_t* sp = A + (size_t)gr * K + k0 + kk;
                v0 = *(const uint4*)sp;
                v1 = *(const uint4*)(sp + 8);
            }
            *(uint4*)(As + r * 32 + kk) = v0;
            *(uint4*)(As + r * 32 + kk + 8) = v1;
        }
        {
            int kk = tid >> 3;
            int n = (tid & 7) * 16;
            const ushort_t* sp = Bm + (size_t)(k0 + kk) * N + col0 + n;
            ushort_t tmp[16];
            if (col0 + n + 16 <= N) {
                *(uint4*)tmp = *(const uint4*)sp;
                *(uint4*)(tmp + 8) = *(const uint4*)(sp + 8);
            } else {
#pragma unroll
                for (int j = 0; j < 16; ++j) {
                    int c = col0 + n + j;
                    tmp[j] = (c < N) ? sp[j] : (ushort_t)0;
                }
            }
#pragma unroll
            for (int j = 0; j < 16; ++j) Bs[(n + j) * 32 + kk] = tmp[j];
        }
        __syncthreads();
        s16x8 af[4], bfr[4];
#pragma unroll
        for (int i = 0; i < 4; ++i)
            af[i] = *(const s16x8*)(As + (wm * 64 + i * 16 + lr) * 32 + lk);
#pragma unroll
        for (int j = 0; j < 4; ++j)
            bfr[j] = *(const s16x8*)(Bs + (wn * 64 + j * 16 + lr) * 32 + lk);
#pragma unroll
        for (int i = 0; i < 4; ++i)
#pragma unroll
            for (int j = 0; j < 4; ++j)
                acc[i][j] = __builtin_amdgcn_mfma_f32_16x16x32_bf16(af[i], bfr[j], acc[i][j], 0, 0, 0);
        __syncthreads();
    }

    const int lrow = (lane >> 4) * 4;
#pragma unroll
    for (int i = 0; i < 4; ++i) {
#pragma unroll
        for (int j = 0; j < 4; ++j) {
            int gr0 = row0 + wm * 64 + i * 16 + lrow;
            int gc = col0 + wn * 64 + j * 16 + lr;
#pragma unroll
            for (int r = 0; r < 4; ++r) {
                int gr = gr0 + r;
                if (gr < M && gc < N) {
                    float v = acc[i][j][r] + bias[gc];
                    if (MODE == 0) {
                        outb[(size_t)gr * N + gc] = f2bf(v);
                    } else {
                        int t = gr >> 5, b = gr & 31;
                        outf[((size_t)(b * TT + t)) * VV + gc] = v;
                    }
                }
            }
        }
    }
}

// ---------------- per-step kernels ----------------

// grid (32,4): block (b, jc) computes a[b][jc*128 .. +128] = h@Wdec + bdec
// block (b,jc) also zeroes ctxU[b][jc*128..+128]; block (b,0) zeroes Ssum[b]
__global__ __launch_bounds__(256) void k_proj(const float* __restrict__ h_in,
                                              const ushort_t* __restrict__ Wdec,
                                              const float* __restrict__ bdec,
                                              float* __restrict__ a_out,
                                              float* __restrict__ ctxU,
                                              float* __restrict__ Ssum) {
    __shared__ float hs[DEC];
    __shared__ float red[4][128];
    const int b = blockIdx.x, jc = blockIdx.y, t = threadIdx.x;
    hs[t] = h_in[b * DEC + t];
    hs[t + 256] = h_in[b * DEC + t + 256];
    __syncthreads();
    const int kh = t >> 6;        // 0..3 -> k slice of 128
    const int jp = t & 63;        // 0..63 -> j pair
    const int j0 = jc * 128 + jp * 2;
    float a0 = 0.f, a1 = 0.f;
    const ushort_t* wp = Wdec + (size_t)(kh * 128) * ATTD + j0;
#pragma unroll 8
    for (int k = 0; k < 128; ++k) {
        uint_t w = *(const uint_t*)(wp + (size_t)k * ATTD);
        float hk = hs[kh * 128 + k];
        a0 += hk * bf2f((ushort_t)(w & 0xffffu));
        a1 += hk * bf2f((ushort_t)(w >> 16));
    }
    red[kh][jp * 2] = a0;
    red[kh][jp * 2 + 1] = a1;
    __syncthreads();
    if (t < 128) {
        int j = jc * 128 + t;
        a_out[b * ATTD + j] = red[0][t] + red[1][t] + red[2][t] + red[3][t] + bdec[j];
        ctxU[b * ENC + j] = 0.f;
        if (jc == 0 && t == 0) Ssum[b] = 0.f;
    }
}

// grid (32,4): block (b, pc) handles 49 p's: scores -> exp (no max needed,
// |score| <= sum|v| ~ 8) -> atomic accumulate unnormalized context and S
__global__ __launch_bounds__(256) void k_attp(const ushort_t* __restrict__ fp,
                                              const ushort_t* __restrict__ fb,
                                              const float* __restrict__ a_in,
                                              const float* __restrict__ vatt,
                                              const float* __restrict__ bfull,
                                              float* __restrict__ ctxU,
                                              float* __restrict__ Ssum) {
    __shared__ float as_[ATTD];
    __shared__ float vs[ATTD];
    __shared__ float ep[64];
    const int b = blockIdx.x, pc = blockIdx.y, t = threadIdx.x;
    as_[t] = a_in[b * ATTD + t];
    as_[t + 256] = a_in[b * ATTD + t + 256];
    vs[t] = vatt[t];
    vs[t + 256] = vatt[t + 256];
    __syncthreads();

    const int pl = t >> 2;          // 0..63 (use <49)
    const int ks = t & 3;           // k slice of 128
    float acc = 0.f;
    if (pl < 49) {
        const int p = pc * 49 + pl;
        const ushort_t* fr = fp + ((size_t)b * PP + p) * ATTD + ks * 128;
#pragma unroll 8
        for (int kk = 0; kk < 128; kk += 2) {
            uint_t fv = *(const uint_t*)(fr + kk);
            int k = ks * 128 + kk;
            acc += ftanh(bf2f((ushort_t)(fv & 0xffffu)) + as_[k]) * vs[k];
            acc += ftanh(bf2f((ushort_t)(fv >> 16)) + as_[k + 1]) * vs[k + 1];
        }
    }
    acc += __shfl_xor(acc, 1);
    acc += __shfl_xor(acc, 2);
    if (ks == 0) ep[pl] = (pl < 49) ? __expf(acc + bfull[0]) : 0.f;
    __syncthreads();

    if (t < 64) {
        float v = ep[t];
#pragma unroll
        for (int off = 32; off > 0; off >>= 1) v += __shfl_xor(v, off);
        if (t == 0) atomicAdd(Ssum + b, v);
    }

    // unnormalized context partial: thread handles cols t and t+256
    float c0 = 0.f, c1 = 0.f;
    const ushort_t* fbp = fb + ((size_t)b * PP + pc * 49) * ENC;
#pragma unroll 4
    for (int p2 = 0; p2 < 49; ++p2) {
        float e2 = ep[p2];
        c0 += e2 * bf2f(fbp[(size_t)p2 * ENC + t]);
        c1 += e2 * bf2f(fbp[(size_t)p2 * ENC + t + 256]);
    }
    atomicAdd(ctxU + b * ENC + t, c0);
    atomicAdd(ctxU + b * ENC + t + 256, c1);
}

// grid 256: block dz owns d-pair {2dz, 2dz+1} x 4 gates x all 32 b.
// Normalizes ctx into LDS, stages h in LDS, f32 dot K=1280, fused pointwise.
__global__ __launch_bounds__(256, 1) void k_gates2(const float* __restrict__ xe_t,
                                                   const float* __restrict__ ctxU,
                                                   const float* __restrict__ Ssum,
                                                   const float* __restrict__ h_in,
                                                   const float* __restrict__ Wih,
                                                   const float* __restrict__ Whh,
                                                   const float* __restrict__ bih,
                                                   const float* __restrict__ bhh,
                                                   float* __restrict__ cbuf,
                                                   float* __restrict__ h_out,
                                                   ushort_t* __restrict__ Hb_t) {
    __shared__ float cs[BB * DEC];    // 64 KB normalized context
    __shared__ float hsL[BB * DEC];   // 64 KB h
    __shared__ float gsr[256];
    __shared__ float invS[BB];
    const int dz = blockIdx.x, t = threadIdx.x;
    if (t < BB) invS[t] = 1.f / Ssum[t];
    __syncthreads();
    for (int i = t; i < BB * DEC; i += 256) {
        cs[i] = ctxU[i] * invS[i >> 9];
        hsL[i] = h_in[i];
    }
    __syncthreads();

    const int b = t >> 3, g = (t >> 1) & 3, ds = t & 1;
    const int d = dz * 2 + ds;
    const int row = g * DEC + d;
    const float* wi = Wih + (size_t)row * (EE + ENC);
    const float* wh = Whh + (size_t)row * DEC;
    const float* xe = xe_t + b * EE;

    f32x4 acc4 = (f32x4){0.f, 0.f, 0.f, 0.f};
#pragma unroll 4
    for (int k = 0; k < EE; k += 4) {
        f32x4 w = *(const f32x4*)(wi + k);
        f32x4 x = *(const f32x4*)(xe + k);
        acc4 += w * x;
    }
#pragma unroll 4
    for (int k = 0; k < ENC; k += 4) {
        f32x4 w = *(const f32x4*)(wi + EE + k);
        f32x4 x = *(const f32x4*)(cs + b * DEC + k);
        acc4 += w * x;
    }
#pragma unroll 4
    for (int k = 0; k < DEC; k += 4) {
        f32x4 w = *(const f32x4*)(wh + k);
        f32x4 x = *(const f32x4*)(hsL + b * DEC + k);
        acc4 += w * x;
    }
    gsr[t] = acc4[0] + acc4[1] + acc4[2] + acc4[3] + bih[row] + bhh[row];
    __syncthreads();

    if (t < 64) {
        const int b2 = t >> 1, d2s = t & 1;
        const int dd = dz * 2 + d2s;
        const int base = b2 * 8 + d2s;
        float vi = gsr[base + 0], vf = gsr[base + 2], vg = gsr[base + 4], vo = gsr[base + 6];
        float cold = cbuf[b2 * DEC + dd];
        float cn = fsig(vf) * cold + fsig(vi) * ftanh(vg);
        float hn = fsig(vo) * ftanh(cn);
        cbuf[b2 * DEC + dd] = cn;
        h_out[b2 * DEC + dd] = hn;
        Hb_t[b2 * DEC + dd] = f2bf(hn);
    }
}

// ---------------- launch ----------------

extern "C" void kernel_launch(void* const* d_in, const int* in_sizes, int n_in,
                              void* d_out, int out_size, void* d_ws, size_t ws_size,
                              hipStream_t stream) {
    const float* features  = (const float*)d_in[0];
    const int*   captions  = (const int*)d_in[1];
    const float* emb       = (const float*)d_in[2];
    const float* W_enc_att = (const float*)d_in[3];
    const float* b_enc_att = (const float*)d_in[4];
    const float* W_dec_att = (const float*)d_in[5];
    const float* b_dec_att = (const float*)d_in[6];
    const float* v_att     = (const float*)d_in[7];
    const float* b_full    = (const float*)d_in[8];
    const float* W_init_h  = (const float*)d_in[9];
    const float* b_init_h  = (const float*)d_in[10];
    const float* W_init_c  = (const float*)d_in[11];
    const float* b_init_c  = (const float*)d_in[12];
    const float* W_ih      = (const float*)d_in[13];
    const float* W_hh      = (const float*)d_in[14];
    const float* b_ih      = (const float*)d_in[15];
    const float* b_hh      = (const float*)d_in[16];
    const float* W_fcn     = (const float*)d_in[17];
    const float* b_fcn     = (const float*)d_in[18];
    float* out = (float*)d_out;
    char* ws = (char*)d_ws;

    size_t o = 0;
    ushort_t* Wfcn_b = (ushort_t*)(ws + o); o += (size_t)DEC * VV * 2;
    ushort_t* Wenc_b = (ushort_t*)(ws + o); o += (size_t)ENC * ATTD * 2;
    ushort_t* Wdec_b = (ushort_t*)(ws + o); o += (size_t)DEC * ATTD * 2;
    ushort_t* fb     = (ushort_t*)(ws + o); o += (size_t)BB * PP * ENC * 2;
    ushort_t* fp_b   = (ushort_t*)(ws + o); o += (size_t)BB * PP * ATTD * 2;
    float*    embeds = (float*)(ws + o);    o += (size_t)TT * BB * EE * 4;
    ushort_t* Hb     = (ushort_t*)(ws + o); o += (size_t)TT * BB * DEC * 2;
    float*    hbuf   = (float*)(ws + o);    o += (size_t)2 * BB * DEC * 4;
    float*    cbuf   = (float*)(ws + o);    o += (size_t)BB * DEC * 4;
    float*    a_buf  = (float*)(ws + o);    o += (size_t)BB * ATTD * 4;
    float*    ctxU   = (float*)(ws + o);    o += (size_t)BB * ENC * 4;
    float*    Ssum   = (float*)(ws + o);    o += (size_t)BB * 4;

    // prep
    k_cvt<<<2048, 256, 0, stream>>>(W_fcn, Wfcn_b, DEC * VV);
    k_cvt<<<256, 256, 0, stream>>>(W_enc_att, Wenc_b, ENC * ATTD);
    k_cvt<<<256, 256, 0, stream>>>(W_dec_att, Wdec_b, DEC * ATTD);
    k_cvt<<<2048, 256, 0, stream>>>(features, fb, BB * PP * ENC);
    k_embed<<<1024, 256, 0, stream>>>(captions, emb, embeds);
    k_init<<<32, 256, 0, stream>>>(features, W_init_h, b_init_h, W_init_c, b_init_c,
                                   hbuf, cbuf);
    k_gemm<0><<<dim3((BB * PP) / 128, ATTD / 128), 256, 0, stream>>>(
        fb, Wenc_b, b_enc_att, fp_b, nullptr, BB * PP, ATTD, ENC);

    // recurrent steps: 3 dispatches each
    for (int t = 0; t < TT; ++t) {
        const float* h_in = hbuf + (size_t)(t & 1) * BB * DEC;
        float* h_out = hbuf + (size_t)((t + 1) & 1) * BB * DEC;
        k_proj<<<dim3(32, 4), 256, 0, stream>>>(h_in, Wdec_b, b_dec_att, a_buf, ctxU, Ssum);
        k_attp<<<dim3(32, 4), 256, 0, stream>>>(fp_b, fb, a_buf, v_att, b_full, ctxU, Ssum);
        k_gates2<<<256, 256, 0, stream>>>(embeds + (size_t)t * BB * EE, ctxU, Ssum, h_in,
                                          W_ih, W_hh, b_ih, b_hh,
                                          cbuf, h_out, Hb + (size_t)t * BB * DEC);
    }

    // out = H @ W_fcn + b_fcn, scattered to [b][t][v]
    k_gemm<1><<<dim3((TT * BB + 127) / 128, (VV + 127) / 128), 256, 0, stream>>>(
        Hb, Wfcn_b, b_fcn, nullptr, out, TT * BB, VV, DEC);
}